// Round 5
// baseline (1064.881 us; speedup 1.0000x reference)
//
#include <hip/hip_runtime.h>
#include <hip/hip_bf16.h>
#include <stdint.h>

// SelfAttentionBlock: B=4,S=4096,C=2048,O=2048,H=8,DH=256
//
// R5: register-pipelined 4-phase gemm256 (reads one phase ahead of use) so
// the LDS drain overlaps the MFMA pipe instead of alternating with it.
//   MFMA q_p at phase p consumes frags read at phase p-1 -> compiler emits
//   counted lgkmcnt(4) (not a drain); LDS unit drains next quadrant's reads
//   WHILE MFMA runs. b(t+1) read post-MFMA-q3 (WAR reuse, saves 32 VGPR).
// Staging ledger (all stages post-GBAR, each provably after the chip-wide
// retirement of the region's reads):
//   ph0: stage A(t+1)->buf c^1      [c^1's aq reads retired at t-1 ph3 lgkm,
//                                    proven chip-wide after t ph0 GBAR]
//   ph1: stage B(t+2)h0 -> buf c    [b(t) reads (issued t-1 ph3) retired at
//   ph2: stage B(t+2)h1 -> buf c     ph0's lgkm, proven after ph1/ph2 GBAR]
//   ph3: vmcnt(4) [t+1 landed: A(t+1) from ph0 + B(t+1) from t-1; leaves
//        B(t+2) 4 loads in flight]; GBAR; read aq0(t+1); MFMA q3; read b(t+1)
// Prologue: A(0),B(0),A(1),B(1) staged; vmcnt(8); GBAR; read b(0)+aq0(0).
// Kept from R4: T2 swizzle (conflicts==0), XCD N-stripe, T5 setprio, 128KB dbuf.
//
// Pipeline (path X, ws >= 288MB):
//   0) x (fp32) -> xbf (bf16)
//   1) transpose+convert Wq|Wk|Wv -> WqkvT bf16 [6144][2048]; Wo -> WoT
//   2) qkv = xbf @ Wqkv + b      (gemm256<N=6144>, grid 1536)
//   3) per-position 8-head attention in fused buffer (attended -> q-slice)
//   4) y = attended @ Wo + bo + x -> out fp32 (gemm256<N=2048>, lda=6144)
//   5) LayerNorm in place on out
// Path Y (ws < 288MB): QKV GEMM uses gemm_f32a (old 128² structure).

using short8  = __attribute__((ext_vector_type(8))) short;
using floatx4 = __attribute__((ext_vector_type(4))) float;

__device__ __forceinline__ float bf2f(ushort u) {
    union { uint32_t i; float f; } v; v.i = ((uint32_t)u) << 16; return v.f;
}
__device__ __forceinline__ ushort f2bf(float f) {
    union { float f; uint32_t i; } v; v.f = f;
    uint32_t r = v.i + 0x7fffu + ((v.i >> 16) & 1u);
    return (ushort)(r >> 16);
}
__device__ __forceinline__ short8 pack8(const floatx4& a, const floatx4& b) {
    short8 o;
    o[0] = (short)f2bf(a[0]); o[1] = (short)f2bf(a[1]);
    o[2] = (short)f2bf(a[2]); o[3] = (short)f2bf(a[3]);
    o[4] = (short)f2bf(b[0]); o[5] = (short)f2bf(b[1]);
    o[6] = (short)f2bf(b[2]); o[7] = (short)f2bf(b[3]);
    return o;
}
__device__ __forceinline__ void async_copy16(const void* g, void* l) {
    __builtin_amdgcn_global_load_lds(
        (__attribute__((address_space(1))) uint32_t*)g,
        (__attribute__((address_space(3))) uint32_t*)l,
        16, 0, 0);
}

#define GBAR do { asm volatile("" ::: "memory"); \
                  __builtin_amdgcn_s_barrier(); \
                  asm volatile("" ::: "memory"); } while (0)

// -------- fp32 -> bf16 bulk convert (8 elems/thread) ------------------------
__global__ void cvt_bf16(const float* __restrict__ in, ushort* __restrict__ out) {
    const size_t base = ((size_t)blockIdx.x * 256 + threadIdx.x) * 8;
    floatx4 a = *(const floatx4*)&in[base];
    floatx4 b = *(const floatx4*)&in[base + 4];
    *(short8*)&out[base] = pack8(a, b);
}

// -------- weight transpose+convert: fp32 [2048][2048] -> bf16 T -------------
__global__ void convT2048(const float* __restrict__ in, ushort* __restrict__ out) {
    __shared__ alignas(16) float tile[32][33];
    const int x = blockIdx.x * 32 + threadIdx.x;
    const int y0 = blockIdx.y * 32;
    for (int j = threadIdx.y; j < 32; j += 8)
        tile[j][threadIdx.x] = in[(size_t)(y0 + j) * 2048 + x];
    __syncthreads();
    const int x2 = blockIdx.y * 32 + threadIdx.x;
    const int y2 = blockIdx.x * 32;
    for (int j = threadIdx.y; j < 32; j += 8)
        out[(size_t)(y2 + j) * 2048 + x2] = f2bf(tile[threadIdx.x][j]);
}

// -------- 256² register-pipelined GEMM: C = A_bf16[M][2048](lda)@Bt^T + bias
template <typename CT, int N>
__global__ __launch_bounds__(512, 2)
void gemm256(const ushort* __restrict__ A, int lda,
             const ushort* __restrict__ Bt,
             const float* __restrict__ b0, const float* __restrict__ b1,
             const float* __restrict__ b2,
             const float* __restrict__ resid, CT* __restrict__ C)
{
    constexpr int K   = 2048;
    constexpr int NKT = K / 64;       // 32 K-tiles
    constexpr int NT  = N / 256;      // N-tiles
    constexpr int SW  = NT / 8;       // stripe width per XCD
    __shared__ alignas(16) ushort lA[2][256 * 64];   // 64KB
    __shared__ alignas(16) ushort lB[2][256 * 64];   // 64KB

    const int t    = threadIdx.x;
    const int wid  = t >> 6, lane = t & 63;
    const int wr   = wid >> 2, wc = wid & 3;         // 2M x 4N waves
    const int lr   = lane & 15, q4 = lane >> 4;
    const int swk  = lr & 7;                          // read-side swizzle key

    // XCD N-stripe decode (each XCD owns SW B-panels, L2-resident; A via L3)
    const int l    = (int)blockIdx.x;
    const int xcd  = l & 7;
    const int j2   = l >> 3;
    const int row0 = (j2 / SW) * 256;
    const int col0 = (xcd * SW + (j2 % SW)) * 256;

    const float* bias; int boff;
    if (col0 < 2048)      { bias = b0; boff = 0; }
    else if (col0 < 4096) { bias = b1; boff = 2048; }
    else                  { bias = b2; boff = 4096; }

    // ---- staging: half-tile = 128 rows x 64 cols = 16KB = 512 thr x 16B.
    // LDS dest linear; global source col pre-swizzled (rule #21).
    const int rpb = t >> 3;                 // row 0..63 (chunk1: +64)
    const int sp  = t & 7;
    const int gc0 = (sp ^ (rpb & 7)) * 8;   // (rpb+64)&7 == rpb&7
    const ushort* pA0 = A  + (size_t)(row0 + rpb)      * lda + gc0;
    const ushort* pA1 = A  + (size_t)(row0 + 64 + rpb) * lda + gc0;
    const ushort* pB0 = Bt + (size_t)(col0 + rpb)      * K   + gc0;
    const ushort* pB1 = Bt + (size_t)(col0 + 64 + rpb) * K   + gc0;

#define STAGE_A(buf, half, kn) do { \
    async_copy16(pA0 + (size_t)(half) * 128 * lda + (kn) * 64, \
                 &lA[buf][(half) * 8192 + t * 8]); \
    async_copy16(pA1 + (size_t)(half) * 128 * lda + (kn) * 64, \
                 &lA[buf][(half) * 8192 + 4096 + t * 8]); \
} while (0)
#define STAGE_B(buf, half, kn) do { \
    async_copy16(pB0 + (size_t)(half) * 128 * K + (kn) * 64, \
                 &lB[buf][(half) * 8192 + t * 8]); \
    async_copy16(pB1 + (size_t)(half) * 128 * K + (kn) * 64, \
                 &lB[buf][(half) * 8192 + 4096 + t * 8]); \
} while (0)

    // ---- fragment read addressing (row*64 ushort + swizzled 16B slot)
    const int arow = (wr * 128 + lr) * 64;
    const int brow = (wc * 64  + lr) * 64;
    const int c0 = ((0 + q4) ^ swk) * 8;    // ks=0 slot
    const int c1 = ((4 + q4) ^ swk) * 8;    // ks=1 slot

    floatx4 acc[8][4];
    #pragma unroll
    for (int i = 0; i < 8; i++)
        #pragma unroll
        for (int j = 0; j < 4; j++)
            acc[i][j] = (floatx4){0.f, 0.f, 0.f, 0.f};

    short8 bfr[4][2];
    short8 aq[4][2][2];   // [quadrant][m-in-quarter][ks]

#define LOAD_AQ(q, buf) do { \
    _Pragma("unroll") \
    for (int m = 0; m < 2; m++) { \
        aq[q][m][0] = *(const short8*)&lA[buf][arow + ((q) * 2 + m) * 1024 + c0]; \
        aq[q][m][1] = *(const short8*)&lA[buf][arow + ((q) * 2 + m) * 1024 + c1]; \
    } \
} while (0)
#define LOAD_B(buf) do { \
    _Pragma("unroll") \
    for (int j = 0; j < 4; j++) { \
        bfr[j][0] = *(const short8*)&lB[buf][brow + j * 1024 + c0]; \
        bfr[j][1] = *(const short8*)&lB[buf][brow + j * 1024 + c1]; \
    } \
} while (0)
#define MFMA_Q(q) do { \
    _Pragma("unroll") \
    for (int m = 0; m < 2; m++) \
        _Pragma("unroll") \
        for (int j = 0; j < 4; j++) \
            _Pragma("unroll") \
            for (int ks = 0; ks < 2; ks++) \
                acc[(q) * 2 + m][j] = __builtin_amdgcn_mfma_f32_16x16x32_bf16( \
                    aq[q][m][ks], bfr[j][ks], acc[(q) * 2 + m][j], 0, 0, 0); \
} while (0)

    // ---- prologue: tiles 0 and 1 staged; tile 0 landed; read b(0)+aq0(0)
    STAGE_A(0, 0, 0); STAGE_A(0, 1, 0);
    STAGE_B(0, 0, 0); STAGE_B(0, 1, 0);
    STAGE_A(1, 0, 1); STAGE_A(1, 1, 1);
    STAGE_B(1, 0, 1); STAGE_B(1, 1, 1);
    asm volatile("s_waitcnt vmcnt(8)" ::: "memory");   // tile 0 landed
    GBAR;
    LOAD_B(0);
    LOAD_AQ(0, 0);

    for (int kt = 0; kt < NKT; ++kt) {
        const int c = kt & 1;

        // ---- ph0: read aq1(t); MFMA q0 (frags from t-1 ph3 / prologue)
        LOAD_AQ(1, c);
        GBAR;
        if (kt >= 1 && kt <= NKT - 2) { STAGE_A(c ^ 1, 0, kt + 1);
                                        STAGE_A(c ^ 1, 1, kt + 1); }
        __builtin_amdgcn_s_setprio(1);
        MFMA_Q(0);
        __builtin_amdgcn_s_setprio(0);

        // ---- ph1: read aq2(t); MFMA q1
        LOAD_AQ(2, c);
        GBAR;
        if (kt <= NKT - 3) STAGE_B(c, 0, kt + 2);
        __builtin_amdgcn_s_setprio(1);
        MFMA_Q(1);
        __builtin_amdgcn_s_setprio(0);

        // ---- ph2: read aq3(t); MFMA q2
        LOAD_AQ(3, c);
        GBAR;
        if (kt <= NKT - 3) STAGE_B(c, 1, kt + 2);
        __builtin_amdgcn_s_setprio(1);
        MFMA_Q(2);
        __builtin_amdgcn_s_setprio(0);

        // ---- ph3: tile t+1 landed; read aq0(t+1); MFMA q3; read b(t+1)
        if (kt <= NKT - 2) {
            if (kt <= NKT - 3) { asm volatile("s_waitcnt vmcnt(4)" ::: "memory"); }
            else               { asm volatile("s_waitcnt vmcnt(0)" ::: "memory"); }
            GBAR;   // chip-wide: t+1 fully in LDS
            LOAD_AQ(0, c ^ 1);
            __builtin_amdgcn_s_setprio(1);
            MFMA_Q(3);
            __builtin_amdgcn_s_setprio(0);
            LOAD_B(c ^ 1);   // WAR on bfr regs: compiler orders after MFMA q3
        } else {
            __builtin_amdgcn_s_setprio(1);
            MFMA_Q(3);
            __builtin_amdgcn_s_setprio(0);
        }
    }
#undef STAGE_A
#undef STAGE_B
#undef LOAD_AQ
#undef LOAD_B
#undef MFMA_Q

    // ---- epilogue: C[row0+wr*128+i*16+q4*4+r][col0+wc*64+j*16+lr]
    #pragma unroll
    for (int j = 0; j < 4; j++) {
        const int gcol = col0 + wc * 64 + j * 16 + lr;
        const float bv = bias[gcol - boff];
        #pragma unroll
        for (int i = 0; i < 8; i++) {
            #pragma unroll
            for (int r = 0; r < 4; r++) {
                const int grow = row0 + wr * 128 + i * 16 + q4 * 4 + r;
                const size_t off = (size_t)grow * N + gcol;
                float v = acc[i][j][r] + bv;
                if (resid) v += resid[off];
                if constexpr (__is_same(CT, float)) C[off] = v;
                else                                C[off] = f2bf(v);
            }
        }
    }
}

// -------- fallback GEMM (path Y): fp32 A staged raw, old 128² structure -----
template <int N>
__global__ __launch_bounds__(256, 2)
void gemm_f32a(const float* __restrict__ A, int lda,
               const ushort* __restrict__ Bt,
               const float* __restrict__ b0, const float* __restrict__ b1,
               const float* __restrict__ b2, ushort* __restrict__ C)
{
    constexpr int K = 2048;
    constexpr int NT = N / 128;
    constexpr int SW = NT / 8;
    __shared__ alignas(16) float  lA32[128 * 32];   // 16KB
    __shared__ alignas(16) ushort lB[128 * 32];     // 8KB

    const int t = threadIdx.x;
    const int wave = t >> 6, lane = t & 63;

    const int l = (int)blockIdx.x;
    const int xcd = l & 7;
    const int j2 = l >> 3;
    const int row0 = (j2 / SW) * 128;
    const int col0 = (xcd * SW + (j2 % SW)) * 128;

    const float* bias; int boff;
    if (col0 < 2048)      { bias = b0; boff = 0; }
    else if (col0 < 4096) { bias = b1; boff = 2048; }
    else                  { bias = b2; boff = 4096; }

    const int ar = t >> 3, ac = (t & 7) * 4;
    const float* gA0 = A + (size_t)(row0 + ar) * lda + ac;
    const ushort* gB0 = Bt + (size_t)(col0 + (t >> 2)) * K + (t & 3) * 8;
    const ushort* gB1 = Bt + (size_t)(col0 + 64 + (t >> 2)) * K + (t & 3) * 8;

    const int wm = (wave >> 1) * 64;
    const int wn = (wave & 1) * 64;
    const int q4 = lane >> 4;
    const int lr = lane & 15;

    floatx4 acc[4][4];
    #pragma unroll
    for (int i = 0; i < 4; i++)
        #pragma unroll
        for (int j = 0; j < 4; j++)
            acc[i][j] = (floatx4){0.f, 0.f, 0.f, 0.f};

    for (int kt = 0; kt < K / 32; ++kt) {
        const int ko = kt * 32;
        #pragma unroll
        for (int n = 0; n < 4; n++)
            async_copy16(gA0 + (size_t)n * 32 * lda + ko, &lA32[(n * 256 + t) * 4]);
        async_copy16(gB0 + ko, &lB[t * 8]);
        async_copy16(gB1 + ko, &lB[2048 + t * 8]);
        __syncthreads();

        short8 af[4], bfr[4];
        #pragma unroll
        for (int i = 0; i < 4; i++) {
            const floatx4* pa = (const floatx4*)&lA32[(wm + i * 16 + lr) * 32 + q4 * 8];
            af[i] = pack8(pa[0], pa[1]);
        }
        #pragma unroll
        for (int j = 0; j < 4; j++)
            bfr[j] = *(const short8*)&lB[(wn + j * 16 + lr) * 32 + q4 * 8];

        #pragma unroll
        for (int i = 0; i < 4; i++)
            #pragma unroll
            for (int j = 0; j < 4; j++)
                acc[i][j] = __builtin_amdgcn_mfma_f32_16x16x32_bf16(
                    af[i], bfr[j], acc[i][j], 0, 0, 0);
        __syncthreads();
    }

    #pragma unroll
    for (int j = 0; j < 4; j++) {
        const int gcol = col0 + wn + j * 16 + lr;
        const float bv = bias[gcol - boff];
        #pragma unroll
        for (int i = 0; i < 4; i++)
            #pragma unroll
            for (int r = 0; r < 4; r++) {
                const int grow = row0 + wm + i * 16 + q4 * 4 + r;
                C[(size_t)grow * N + gcol] = f2bf(acc[i][j][r] + bv);
            }
    }
}

// -------- per-position attention on fused qkv [16384][6144], bf16 ----------
__global__ __launch_bounds__(256, 2)
void attn_kernel(ushort* __restrict__ qkv)
{
    __shared__ alignas(16) ushort sq[4][2048];
    __shared__ alignas(16) ushort sk[4][2048];
    __shared__ alignas(16) ushort sv[4][2048];
    const int wave = threadIdx.x >> 6, lane = threadIdx.x & 63;
    const size_t p = (size_t)blockIdx.x * 4 + wave;
    const size_t base = p * 6144;

    #pragma unroll
    for (int c = 0; c < 4; c++) {
        const int idx = c * 512 + lane * 8;
        *(short8*)&sq[wave][idx] = *(const short8*)&qkv[base + idx];
        *(short8*)&sk[wave][idx] = *(const short8*)&qkv[base + 2048 + idx];
        *(short8*)&sv[wave][idx] = *(const short8*)&qkv[base + 4096 + idx];
    }

    const int h = lane >> 3;
    const int tt = lane & 7;
    float s = 0.f;
    #pragma unroll 4
    for (int c = 0; c < 32; c++) {
        short8 qv = *(const short8*)&sq[wave][h * 256 + c * 8];
        short8 kv = *(const short8*)&sk[wave][tt * 256 + c * 8];
        #pragma unroll
        for (int e = 0; e < 8; e++)
            s += bf2f((ushort)qv[e]) * bf2f((ushort)kv[e]);
    }
    s *= (1.0f / 16.0f);   // 1/sqrt(256)

    float m = s;
    m = fmaxf(m, __shfl_xor(m, 1));
    m = fmaxf(m, __shfl_xor(m, 2));
    m = fmaxf(m, __shfl_xor(m, 4));
    float e = __expf(s - m);
    float sum = e;
    sum += __shfl_xor(sum, 1);
    sum += __shfl_xor(sum, 2);
    sum += __shfl_xor(sum, 4);
    const float w = e / sum;

    float wt[8];
    #pragma unroll
    for (int t2 = 0; t2 < 8; t2++)
        wt[t2] = __shfl(w, (lane & 56) + t2);

    const int d0 = (lane & 7) * 8;
    #pragma unroll
    for (int c = 0; c < 4; c++) {
        const int d = d0 + c * 64;
        float acc[8] = {0, 0, 0, 0, 0, 0, 0, 0};
        #pragma unroll
        for (int t2 = 0; t2 < 8; t2++) {
            short8 vv = *(const short8*)&sv[wave][t2 * 256 + d];
            #pragma unroll
            for (int e2 = 0; e2 < 8; e2++)
                acc[e2] += wt[t2] * bf2f((ushort)vv[e2]);
        }
        short8 o;
        #pragma unroll
        for (int e2 = 0; e2 < 8; e2++)
            o[e2] = (short)f2bf(acc[e2]);
        *(short8*)&qkv[base + h * 256 + d] = o;
    }
}

// -------- LayerNorm over C=2048, fp32 in place on d_out ---------------------
__global__ __launch_bounds__(256, 2)
void ln_kernel(float* __restrict__ y, const float* __restrict__ gamma,
               const float* __restrict__ beta)
{
    __shared__ float red[2][4];
    const int t = threadIdx.x;
    const size_t base = (size_t)blockIdx.x * 2048 + t * 8;
    floatx4 a = *(const floatx4*)&y[base];
    floatx4 b = *(const floatx4*)&y[base + 4];
    float f[8] = {a[0], a[1], a[2], a[3], b[0], b[1], b[2], b[3]};
    float s = 0.f, ss = 0.f;
    #pragma unroll
    for (int e = 0; e < 8; e++) { s += f[e]; ss += f[e] * f[e]; }
    #pragma unroll
    for (int off = 1; off < 64; off <<= 1) {
        s  += __shfl_xor(s, off);
        ss += __shfl_xor(ss, off);
    }
    const int wave = t >> 6, lane = t & 63;
    if (lane == 0) { red[0][wave] = s; red[1][wave] = ss; }
    __syncthreads();
    s  = red[0][0] + red[0][1] + red[0][2] + red[0][3];
    ss = red[1][0] + red[1][1] + red[1][2] + red[1][3];
    const float mu  = s * (1.f / 2048.f);
    const float var = fmaxf(ss * (1.f / 2048.f) - mu * mu, 0.f);
    const float rs  = rsqrtf(var + 1e-5f);
    floatx4 g0 = *(const floatx4*)&gamma[t * 8];
    floatx4 g1 = *(const floatx4*)&gamma[t * 8 + 4];
    floatx4 b0 = *(const floatx4*)&beta[t * 8];
    floatx4 b1 = *(const floatx4*)&beta[t * 8 + 4];
    floatx4 o0, o1;
    #pragma unroll
    for (int e = 0; e < 4; e++) {
        o0[e] = g0[e] * (f[e] - mu) * rs + b0[e];
        o1[e] = g1[e] * (f[e + 4] - mu) * rs + b1[e];
    }
    *(floatx4*)&y[base]     = o0;
    *(floatx4*)&y[base + 4] = o1;
}

extern "C" void kernel_launch(void* const* d_in, const int* in_sizes, int n_in,
                              void* d_out, int out_size, void* d_ws, size_t ws_size,
                              hipStream_t stream)
{
    const float* x     = (const float*)d_in[0];
    const float* Wq    = (const float*)d_in[1];
    const float* bq    = (const float*)d_in[2];
    const float* Wk    = (const float*)d_in[3];
    const float* bk    = (const float*)d_in[4];
    const float* Wv    = (const float*)d_in[5];
    const float* bv    = (const float*)d_in[6];
    const float* Wo    = (const float*)d_in[7];
    const float* bo    = (const float*)d_in[8];
    const float* gamma = (const float*)d_in[9];
    const float* beta  = (const float*)d_in[10];
    float* out = (float*)d_out;

    char* ws = (char*)d_ws;
    const size_t MB = 1024 * 1024;
    ushort* WqkvT = (ushort*)(ws + 0 * MB);    // 24MB: Wq^T | Wk^T | Wv^T rows
    ushort* WoT   = (ushort*)(ws + 24 * MB);   // 8MB

    const bool bigws = ws_size >= 288 * MB;
    ushort* xbf = (ushort*)(ws + 32 * MB);                      // path X: 64MB
    ushort* qkv = (ushort*)(ws + (bigws ? 96 : 32) * MB);       // 192MB fused

    dim3 tb(32, 8), tg(64, 64);
    convT2048<<<tg, tb, 0, stream>>>(Wq, WqkvT);
    convT2048<<<tg, tb, 0, stream>>>(Wk, WqkvT + 2048 * 2048);
    convT2048<<<tg, tb, 0, stream>>>(Wv, WqkvT + 2 * 2048 * 2048);
    convT2048<<<tg, tb, 0, stream>>>(Wo, WoT);

    if (bigws) {
        cvt_bf16<<<16384, 256, 0, stream>>>(x, xbf);
        // fused QKV: [16384][2048] @ [6144][2048]^T -> [16384][6144]
        gemm256<ushort, 6144><<<1536, 512, 0, stream>>>(
            xbf, 2048, WqkvT, bq, bk, bv, nullptr, qkv);
    } else {
        gemm_f32a<6144><<<6144, 256, 0, stream>>>(
            x, 2048, WqkvT, bq, bk, bv, qkv);
    }

    attn_kernel<<<4096, 256, 0, stream>>>(qkv);

    // attended lives in q-slice of fused buffer (lda=6144)
    gemm256<float, 2048><<<512, 512, 0, stream>>>(
        qkv, 6144, WoT, bo, bo, bo, x, out);

    ln_kernel<<<16384, 256, 0, stream>>>(out, gamma, beta);
}

// Round 7
// 879.270 us; speedup vs baseline: 1.2111x; 1.2111x over previous
//
#include <hip/hip_runtime.h>
#include <hip/hip_bf16.h>
#include <stdint.h>

// SelfAttentionBlock: B=4,S=4096,C=2048,O=2048,H=8,DH=256
//
// R7 = R6 resubmit (R6 bench died on container-acquisition infra error; code
// audited for hang/OOB/barrier-divergence classes -> clean, resubmitting
// unchanged to preserve the A/B vs R4/R5).
//
// R6: K-loop = R4 schedule verbatim (best: 419us QKV, 45% MfmaUtil).
// Changes:
//   - LDS-transposed epilogue: acc -> lA (64KB, 4 passes of 64 rows) ->
//     coalesced float4/short8 C-writes (1KB/wave-inst vs 4x64B scatter).
//   - Residual add moved from Wo epilogue into ln_kernel (reads x there):
//     removes 128MB of scattered fp32 loads from the 2-round, 1-block/CU
//     Wo dispatch where they are latency-exposed.
// Kept: T2 swizzle (conflicts 0), XCD N-stripe, T5 setprio, 128KB dbuf,
// counted vmcnt(4) boundary (T4).
//
// Pipeline (path X, ws >= 288MB):
//   0) x (fp32) -> xbf (bf16)
//   1) transpose+convert Wq|Wk|Wv -> WqkvT bf16 [6144][2048]; Wo -> WoT
//   2) qkv = xbf @ Wqkv + b      (gemm256<N=6144>, grid 1536)
//   3) per-position 8-head attention in fused buffer (attended -> q-slice)
//   4) out = attended @ Wo + bo   (gemm256<N=2048>, lda=6144, no resid)
//   5) LayerNorm over (out + x) in place on out
// Path Y (ws < 288MB): QKV GEMM uses gemm_f32a (old 128² structure).

using short8  = __attribute__((ext_vector_type(8))) short;
using floatx4 = __attribute__((ext_vector_type(4))) float;

__device__ __forceinline__ float bf2f(ushort u) {
    union { uint32_t i; float f; } v; v.i = ((uint32_t)u) << 16; return v.f;
}
__device__ __forceinline__ ushort f2bf(float f) {
    union { float f; uint32_t i; } v; v.f = f;
    uint32_t r = v.i + 0x7fffu + ((v.i >> 16) & 1u);
    return (ushort)(r >> 16);
}
__device__ __forceinline__ short8 pack8(const floatx4& a, const floatx4& b) {
    short8 o;
    o[0] = (short)f2bf(a[0]); o[1] = (short)f2bf(a[1]);
    o[2] = (short)f2bf(a[2]); o[3] = (short)f2bf(a[3]);
    o[4] = (short)f2bf(b[0]); o[5] = (short)f2bf(b[1]);
    o[6] = (short)f2bf(b[2]); o[7] = (short)f2bf(b[3]);
    return o;
}
__device__ __forceinline__ void async_copy16(const void* g, void* l) {
    __builtin_amdgcn_global_load_lds(
        (__attribute__((address_space(1))) uint32_t*)g,
        (__attribute__((address_space(3))) uint32_t*)l,
        16, 0, 0);
}

#define GBAR do { asm volatile("" ::: "memory"); \
                  __builtin_amdgcn_s_barrier(); \
                  asm volatile("" ::: "memory"); } while (0)
#define LGKM0 asm volatile("s_waitcnt lgkmcnt(0)" ::: "memory")

// -------- fp32 -> bf16 bulk convert (8 elems/thread) ------------------------
__global__ void cvt_bf16(const float* __restrict__ in, ushort* __restrict__ out) {
    const size_t base = ((size_t)blockIdx.x * 256 + threadIdx.x) * 8;
    floatx4 a = *(const floatx4*)&in[base];
    floatx4 b = *(const floatx4*)&in[base + 4];
    *(short8*)&out[base] = pack8(a, b);
}

// -------- weight transpose+convert: fp32 [2048][2048] -> bf16 T -------------
__global__ void convT2048(const float* __restrict__ in, ushort* __restrict__ out) {
    __shared__ alignas(16) float tile[32][33];
    const int x = blockIdx.x * 32 + threadIdx.x;
    const int y0 = blockIdx.y * 32;
    for (int j = threadIdx.y; j < 32; j += 8)
        tile[j][threadIdx.x] = in[(size_t)(y0 + j) * 2048 + x];
    __syncthreads();
    const int x2 = blockIdx.y * 32 + threadIdx.x;
    const int y2 = blockIdx.x * 32;
    for (int j = threadIdx.y; j < 32; j += 8)
        out[(size_t)(y2 + j) * 2048 + x2] = f2bf(tile[threadIdx.x][j]);
}

// -------- 256² 8-phase GEMM (R4 schedule): C = A[M][2048](lda)@Bt^T + bias --
template <typename CT, int N>
__global__ __launch_bounds__(512, 2)
void gemm256(const ushort* __restrict__ A, int lda,
             const ushort* __restrict__ Bt,
             const float* __restrict__ b0, const float* __restrict__ b1,
             const float* __restrict__ b2,
             CT* __restrict__ C)
{
    constexpr int K   = 2048;
    constexpr int NKT = K / 64;       // 32 K-tiles
    constexpr int NT  = N / 256;      // N-tiles
    constexpr int SW  = NT / 8;       // stripe width per XCD
    __shared__ alignas(16) ushort lA[2][256 * 64];   // 64KB
    __shared__ alignas(16) ushort lB[2][256 * 64];   // 64KB

    const int t    = threadIdx.x;
    const int wid  = t >> 6, lane = t & 63;
    const int wr   = wid >> 2, wc = wid & 3;         // 2M x 4N waves
    const int lr   = lane & 15, q4 = lane >> 4;
    const int swk  = lr & 7;                          // read-side swizzle key

    // XCD N-stripe decode (each XCD owns SW B-panels, L2-resident; A via L3)
    const int l    = (int)blockIdx.x;
    const int xcd  = l & 7;
    const int j2   = l >> 3;
    const int row0 = (j2 / SW) * 256;
    const int col0 = (xcd * SW + (j2 % SW)) * 256;

    const float* bias; int boff;
    if (col0 < 2048)      { bias = b0; boff = 0; }
    else if (col0 < 4096) { bias = b1; boff = 2048; }
    else                  { bias = b2; boff = 4096; }

    // ---- staging: half-tile = 128 rows x 64 cols = 16KB = 512 thr x 16B.
    // LDS dest linear; global source col pre-swizzled (rule #21).
    const int rpb = t >> 3;                 // row 0..63 (chunk1: +64)
    const int sp  = t & 7;
    const int gc0 = (sp ^ (rpb & 7)) * 8;   // (rpb+64)&7 == rpb&7
    const ushort* pA0 = A  + (size_t)(row0 + rpb)      * lda + gc0;
    const ushort* pA1 = A  + (size_t)(row0 + 64 + rpb) * lda + gc0;
    const ushort* pB0 = Bt + (size_t)(col0 + rpb)      * K   + gc0;
    const ushort* pB1 = Bt + (size_t)(col0 + 64 + rpb) * K   + gc0;

#define STAGE_A(buf, half, kn) do { \
    async_copy16(pA0 + (size_t)(half) * 128 * lda + (kn) * 64, \
                 &lA[buf][(half) * 8192 + t * 8]); \
    async_copy16(pA1 + (size_t)(half) * 128 * lda + (kn) * 64, \
                 &lA[buf][(half) * 8192 + 4096 + t * 8]); \
} while (0)
#define STAGE_B(buf, half, kn) do { \
    async_copy16(pB0 + (size_t)(half) * 128 * K + (kn) * 64, \
                 &lB[buf][(half) * 8192 + t * 8]); \
    async_copy16(pB1 + (size_t)(half) * 128 * K + (kn) * 64, \
                 &lB[buf][(half) * 8192 + 4096 + t * 8]); \
} while (0)

    // ---- fragment read addressing (row*64 ushort + swizzled 16B slot)
    const int arow = (wr * 128 + lr) * 64;
    const int brow = (wc * 64  + lr) * 64;
    const int c0 = ((0 + q4) ^ swk) * 8;    // ks=0 slot
    const int c1 = ((4 + q4) ^ swk) * 8;    // ks=1 slot

    floatx4 acc[8][4];
    #pragma unroll
    for (int i = 0; i < 8; i++)
        #pragma unroll
        for (int j = 0; j < 4; j++)
            acc[i][j] = (floatx4){0.f, 0.f, 0.f, 0.f};

    short8 bfr[4][2];
    short8 aq[4][2][2];   // [quadrant][m-in-quadrant][ks]

#define LOAD_AQ(q) do { \
    _Pragma("unroll") \
    for (int m = 0; m < 2; m++) { \
        aq[q][m][0] = *(const short8*)&lA[c][arow + ((q) * 2 + m) * 1024 + c0]; \
        aq[q][m][1] = *(const short8*)&lA[c][arow + ((q) * 2 + m) * 1024 + c1]; \
    } \
} while (0)
#define MFMA_Q(q) do { \
    _Pragma("unroll") \
    for (int m = 0; m < 2; m++) \
        _Pragma("unroll") \
        for (int j = 0; j < 4; j++) \
            _Pragma("unroll") \
            for (int ks = 0; ks < 2; ks++) \
                acc[(q) * 2 + m][j] = __builtin_amdgcn_mfma_f32_16x16x32_bf16( \
                    aq[q][m][ks], bfr[j][ks], acc[(q) * 2 + m][j], 0, 0, 0); \
} while (0)

    // ---- prologue: K-tile 0 fully + A-halves of K-tile 1 in flight
    STAGE_A(0, 0, 0); STAGE_A(0, 1, 0);
    STAGE_B(0, 0, 0); STAGE_B(0, 1, 0);
    STAGE_A(1, 0, 1); STAGE_A(1, 1, 1);
    asm volatile("s_waitcnt vmcnt(4)" ::: "memory");   // K-tile 0 landed
    GBAR;

    for (int kt = 0; kt < NKT; ++kt) {
        const int c = kt & 1;

        // ---- phase 1: B(8) + Aq0(4) + Aq1(4); MFMA q0
        #pragma unroll
        for (int j = 0; j < 2; j++) {
            bfr[j][0] = *(const short8*)&lB[c][brow + j * 1024 + c0];
            bfr[j][1] = *(const short8*)&lB[c][brow + j * 1024 + c1];
        }
        LOAD_AQ(0);
        #pragma unroll
        for (int j = 2; j < 4; j++) {
            bfr[j][0] = *(const short8*)&lB[c][brow + j * 1024 + c0];
            bfr[j][1] = *(const short8*)&lB[c][brow + j * 1024 + c1];
        }
        LOAD_AQ(1);
        if (kt < NKT - 1) STAGE_B(c ^ 1, 0, kt + 1);
        GBAR;
        __builtin_amdgcn_s_setprio(1);
        MFMA_Q(0);
        __builtin_amdgcn_s_setprio(0);

        // ---- phase 2: Aq2(4); MFMA q1 (frags issued last phase)
        LOAD_AQ(2);
        if (kt < NKT - 1) STAGE_B(c ^ 1, 1, kt + 1);
        GBAR;
        __builtin_amdgcn_s_setprio(1);
        MFMA_Q(1);
        __builtin_amdgcn_s_setprio(0);

        // ---- phase 3: Aq3(4); MFMA q2
        LOAD_AQ(3);
        GBAR;
        __builtin_amdgcn_s_setprio(1);
        MFMA_Q(2);
        __builtin_amdgcn_s_setprio(0);

        // ---- phase 4: all db[c] reads retired -> stage A(kt+2); MFMA q3
        LGKM0;
        GBAR;   // chip-wide: every wave's reads of db[c] done -> safe to DMA
        if (kt < NKT - 2) { STAGE_A(c, 0, kt + 2); STAGE_A(c, 1, kt + 2); }
        __builtin_amdgcn_s_setprio(1);
        MFMA_Q(3);
        __builtin_amdgcn_s_setprio(0);
        // counted boundary wait: A(kt+1),B(kt+1) landed; A(kt+2) in flight
        if (kt < NKT - 2)       { asm volatile("s_waitcnt vmcnt(4)" ::: "memory"); }
        else if (kt == NKT - 2) { asm volatile("s_waitcnt vmcnt(0)" ::: "memory"); }
        if (kt < NKT - 1) GBAR;
    }
#undef STAGE_A
#undef STAGE_B
#undef LOAD_AQ
#undef MFMA_Q

    // ---- epilogue via LDS transpose: coalesced full-width C writes.
    // acc[i][j][r] holds C(row0 + wr*128 + i*16 + q4*4 + r,
    //                      col0 + wc*64 + j*16 + lr).
    // 4 passes of 64 rows through lA (64KB = 64 x 256 fp32).
    float* sC = (float*)lA;
    const int tcol = (t & 31) * 8;
    #pragma unroll
    for (int p = 0; p < 4; ++p) {
        __syncthreads();                       // prior lA use / prior pass done
        if (wr == (p >> 1)) {
            const int ib = (p & 1) * 4;        // i range [ib, ib+4)
            #pragma unroll
            for (int i2 = 0; i2 < 4; i2++)
                #pragma unroll
                for (int j = 0; j < 4; j++)
                    #pragma unroll
                    for (int r = 0; r < 4; r++)
                        sC[(i2 * 16 + q4 * 4 + r) * 256 + wc * 64 + j * 16 + lr]
                            = acc[ib + i2][j][r];
        }
        __syncthreads();
        #pragma unroll
        for (int r2 = 0; r2 < 4; ++r2) {
            const int lrow = r2 * 16 + (t >> 5);
            const int grow = row0 + p * 64 + lrow;
            floatx4 v0 = *(const floatx4*)&sC[lrow * 256 + tcol];
            floatx4 v1 = *(const floatx4*)&sC[lrow * 256 + tcol + 4];
            const int gcol = col0 + tcol;
            #pragma unroll
            for (int e = 0; e < 4; e++) {
                v0[e] += bias[gcol + e - boff];
                v1[e] += bias[gcol + 4 + e - boff];
            }
            if constexpr (__is_same(CT, float)) {
                *(floatx4*)&C[(size_t)grow * N + gcol]     = v0;
                *(floatx4*)&C[(size_t)grow * N + gcol + 4] = v1;
            } else {
                *(short8*)&C[(size_t)grow * N + gcol] = pack8(v0, v1);
            }
        }
    }
}

// -------- fallback GEMM (path Y): fp32 A staged raw, old 128² structure -----
template <int N>
__global__ __launch_bounds__(256, 2)
void gemm_f32a(const float* __restrict__ A, int lda,
               const ushort* __restrict__ Bt,
               const float* __restrict__ b0, const float* __restrict__ b1,
               const float* __restrict__ b2, ushort* __restrict__ C)
{
    constexpr int K = 2048;
    constexpr int NT = N / 128;
    constexpr int SW = NT / 8;
    __shared__ alignas(16) float  lA32[128 * 32];   // 16KB
    __shared__ alignas(16) ushort lB[128 * 32];     // 8KB

    const int t = threadIdx.x;
    const int wave = t >> 6, lane = t & 63;

    const int l = (int)blockIdx.x;
    const int xcd = l & 7;
    const int j2 = l >> 3;
    const int row0 = (j2 / SW) * 128;
    const int col0 = (xcd * SW + (j2 % SW)) * 128;

    const float* bias; int boff;
    if (col0 < 2048)      { bias = b0; boff = 0; }
    else if (col0 < 4096) { bias = b1; boff = 2048; }
    else                  { bias = b2; boff = 4096; }

    const int ar = t >> 3, ac = (t & 7) * 4;
    const float* gA0 = A + (size_t)(row0 + ar) * lda + ac;
    const ushort* gB0 = Bt + (size_t)(col0 + (t >> 2)) * K + (t & 3) * 8;
    const ushort* gB1 = Bt + (size_t)(col0 + 64 + (t >> 2)) * K + (t & 3) * 8;

    const int wm = (wave >> 1) * 64;
    const int wn = (wave & 1) * 64;
    const int q4 = lane >> 4;
    const int lr = lane & 15;

    floatx4 acc[4][4];
    #pragma unroll
    for (int i = 0; i < 4; i++)
        #pragma unroll
        for (int j = 0; j < 4; j++)
            acc[i][j] = (floatx4){0.f, 0.f, 0.f, 0.f};

    for (int kt = 0; kt < K / 32; ++kt) {
        const int ko = kt * 32;
        #pragma unroll
        for (int n = 0; n < 4; n++)
            async_copy16(gA0 + (size_t)n * 32 * lda + ko, &lA32[(n * 256 + t) * 4]);
        async_copy16(gB0 + ko, &lB[t * 8]);
        async_copy16(gB1 + ko, &lB[2048 + t * 8]);
        __syncthreads();

        short8 af[4], bfr[4];
        #pragma unroll
        for (int i = 0; i < 4; i++) {
            const floatx4* pa = (const floatx4*)&lA32[(wm + i * 16 + lr) * 32 + q4 * 8];
            af[i] = pack8(pa[0], pa[1]);
        }
        #pragma unroll
        for (int j = 0; j < 4; j++)
            bfr[j] = *(const short8*)&lB[(wn + j * 16 + lr) * 32 + q4 * 8];

        #pragma unroll
        for (int i = 0; i < 4; i++)
            #pragma unroll
            for (int j = 0; j < 4; j++)
                acc[i][j] = __builtin_amdgcn_mfma_f32_16x16x32_bf16(
                    af[i], bfr[j], acc[i][j], 0, 0, 0);
        __syncthreads();
    }

    #pragma unroll
    for (int j = 0; j < 4; j++) {
        const int gcol = col0 + wn + j * 16 + lr;
        const float bv = bias[gcol - boff];
        #pragma unroll
        for (int i = 0; i < 4; i++)
            #pragma unroll
            for (int r = 0; r < 4; r++) {
                const int grow = row0 + wm + i * 16 + q4 * 4 + r;
                C[(size_t)grow * N + gcol] = f2bf(acc[i][j][r] + bv);
            }
    }
}

// -------- per-position attention on fused qkv [16384][6144], bf16 ----------
__global__ __launch_bounds__(256, 2)
void attn_kernel(ushort* __restrict__ qkv)
{
    __shared__ alignas(16) ushort sq[4][2048];
    __shared__ alignas(16) ushort sk[4][2048];
    __shared__ alignas(16) ushort sv[4][2048];
    const int wave = threadIdx.x >> 6, lane = threadIdx.x & 63;
    const size_t p = (size_t)blockIdx.x * 4 + wave;
    const size_t base = p * 6144;

    #pragma unroll
    for (int c = 0; c < 4; c++) {
        const int idx = c * 512 + lane * 8;
        *(short8*)&sq[wave][idx] = *(const short8*)&qkv[base + idx];
        *(short8*)&sk[wave][idx] = *(const short8*)&qkv[base + 2048 + idx];
        *(short8*)&sv[wave][idx] = *(const short8*)&qkv[base + 4096 + idx];
    }

    const int h = lane >> 3;
    const int tt = lane & 7;
    float s = 0.f;
    #pragma unroll 4
    for (int c = 0; c < 32; c++) {
        short8 qv = *(const short8*)&sq[wave][h * 256 + c * 8];
        short8 kv = *(const short8*)&sk[wave][tt * 256 + c * 8];
        #pragma unroll
        for (int e = 0; e < 8; e++)
            s += bf2f((ushort)qv[e]) * bf2f((ushort)kv[e]);
    }
    s *= (1.0f / 16.0f);   // 1/sqrt(256)

    float m = s;
    m = fmaxf(m, __shfl_xor(m, 1));
    m = fmaxf(m, __shfl_xor(m, 2));
    m = fmaxf(m, __shfl_xor(m, 4));
    float e = __expf(s - m);
    float sum = e;
    sum += __shfl_xor(sum, 1);
    sum += __shfl_xor(sum, 2);
    sum += __shfl_xor(sum, 4);
    const float w = e / sum;

    float wt[8];
    #pragma unroll
    for (int t2 = 0; t2 < 8; t2++)
        wt[t2] = __shfl(w, (lane & 56) + t2);

    const int d0 = (lane & 7) * 8;
    #pragma unroll
    for (int c = 0; c < 4; c++) {
        const int d = d0 + c * 64;
        float acc[8] = {0, 0, 0, 0, 0, 0, 0, 0};
        #pragma unroll
        for (int t2 = 0; t2 < 8; t2++) {
            short8 vv = *(const short8*)&sv[wave][t2 * 256 + d];
            #pragma unroll
            for (int e2 = 0; e2 < 8; e2++)
                acc[e2] += wt[t2] * bf2f((ushort)vv[e2]);
        }
        short8 o;
        #pragma unroll
        for (int e2 = 0; e2 < 8; e2++)
            o[e2] = (short)f2bf(acc[e2]);
        *(short8*)&qkv[base + h * 256 + d] = o;
    }
}

// -------- LayerNorm over C=2048: y = LN(out + x), fp32, in place on out -----
__global__ __launch_bounds__(256, 2)
void ln_kernel(float* __restrict__ y, const float* __restrict__ x,
               const float* __restrict__ gamma, const float* __restrict__ beta)
{
    __shared__ float red[2][4];
    const int t = threadIdx.x;
    const size_t base = (size_t)blockIdx.x * 2048 + t * 8;
    floatx4 a  = *(const floatx4*)&y[base];
    floatx4 b  = *(const floatx4*)&y[base + 4];
    floatx4 xa = *(const floatx4*)&x[base];
    floatx4 xb = *(const floatx4*)&x[base + 4];
    float f[8] = {a[0] + xa[0], a[1] + xa[1], a[2] + xa[2], a[3] + xa[3],
                  b[0] + xb[0], b[1] + xb[1], b[2] + xb[2], b[3] + xb[3]};
    float s = 0.f, ss = 0.f;
    #pragma unroll
    for (int e = 0; e < 8; e++) { s += f[e]; ss += f[e] * f[e]; }
    #pragma unroll
    for (int off = 1; off < 64; off <<= 1) {
        s  += __shfl_xor(s, off);
        ss += __shfl_xor(ss, off);
    }
    const int wave = t >> 6, lane = t & 63;
    if (lane == 0) { red[0][wave] = s; red[1][wave] = ss; }
    __syncthreads();
    s  = red[0][0] + red[0][1] + red[0][2] + red[0][3];
    ss = red[1][0] + red[1][1] + red[1][2] + red[1][3];
    const float mu  = s * (1.f / 2048.f);
    const float var = fmaxf(ss * (1.f / 2048.f) - mu * mu, 0.f);
    const float rs  = rsqrtf(var + 1e-5f);
    floatx4 g0 = *(const floatx4*)&gamma[t * 8];
    floatx4 g1 = *(const floatx4*)&gamma[t * 8 + 4];
    floatx4 b0 = *(const floatx4*)&beta[t * 8];
    floatx4 b1 = *(const floatx4*)&beta[t * 8 + 4];
    floatx4 o0, o1;
    #pragma unroll
    for (int e = 0; e < 4; e++) {
        o0[e] = g0[e] * (f[e] - mu) * rs + b0[e];
        o1[e] = g1[e] * (f[e + 4] - mu) * rs + b1[e];
    }
    *(floatx4*)&y[base]     = o0;
    *(floatx4*)&y[base + 4] = o1;
}

extern "C" void kernel_launch(void* const* d_in, const int* in_sizes, int n_in,
                              void* d_out, int out_size, void* d_ws, size_t ws_size,
                              hipStream_t stream)
{
    const float* x     = (const float*)d_in[0];
    const float* Wq    = (const float*)d_in[1];
    const float* bq    = (const float*)d_in[2];
    const float* Wk    = (const float*)d_in[3];
    const float* bk    = (const float*)d_in[4];
    const float* Wv    = (const float*)d_in[5];
    const float* bv    = (const float*)d_in[6];
    const float* Wo    = (const float*)d_in[7];
    const float* bo    = (const float*)d_in[8];
    const float* gamma = (const float*)d_in[9];
    const float* beta  = (const float*)d_in[10];
    float* out = (float*)d_out;

    char* ws = (char*)d_ws;
    const size_t MB = 1024 * 1024;
    ushort* WqkvT = (ushort*)(ws + 0 * MB);    // 24MB: Wq^T | Wk^T | Wv^T rows
    ushort* WoT   = (ushort*)(ws + 24 * MB);   // 8MB

    const bool bigws = ws_size >= 288 * MB;
    ushort* xbf = (ushort*)(ws + 32 * MB);                      // path X: 64MB
    ushort* qkv = (ushort*)(ws + (bigws ? 96 : 32) * MB);       // 192MB fused

    dim3 tb(32, 8), tg(64, 64);
    convT2048<<<tg, tb, 0, stream>>>(Wq, WqkvT);
    convT2048<<<tg, tb, 0, stream>>>(Wk, WqkvT + 2048 * 2048);
    convT2048<<<tg, tb, 0, stream>>>(Wv, WqkvT + 2 * 2048 * 2048);
    convT2048<<<tg, tb, 0, stream>>>(Wo, WoT);

    if (bigws) {
        cvt_bf16<<<16384, 256, 0, stream>>>(x, xbf);
        // fused QKV: [16384][2048] @ [6144][2048]^T -> [16384][6144]
        gemm256<ushort, 6144><<<1536, 512, 0, stream>>>(
            xbf, 2048, WqkvT, bq, bk, bv, qkv);
    } else {
        gemm_f32a<6144><<<6144, 256, 0, stream>>>(
            x, 2048, WqkvT, bq, bk, bv, qkv);
    }

    attn_kernel<<<4096, 256, 0, stream>>>(qkv);

    // attended lives in q-slice of fused buffer (lda=6144); no resid here
    gemm256<float, 2048><<<512, 512, 0, stream>>>(
        qkv, 6144, WoT, bo, bo, bo, out);

    // y = LN(out + x)
    ln_kernel<<<16384, 256, 0, stream>>>(out, x, gamma, beta);
}